// Round 8
// baseline (444.942 us; speedup 1.0000x reference)
//
#include <hip/hip_runtime.h>
#include <math.h>

#define B_   8
#define C_   128
#define T_   64
#define N_   256
#define NSEQ 4

typedef __attribute__((ext_vector_type(8))) short bf16x8;
typedef __attribute__((ext_vector_type(4))) float f32x4;
typedef unsigned short ushort_t;

#define LOG2E 1.4426950408889634f
#define LN2   0.6931471805599453f

// ---- LDS word layout (18560 words = 74240 B) ----
// RH/RL: P0/P1 = split H; P5/P6 = split Y (region dead between P1 and P5)
#define RH   0       // [64][68] u32 (hi-plane pairs)
#define RL   4352    // [64][68] u32 (lo-plane pairs)
#define R1   8704    // [128][67] f32: silu(z), [d][t]
#define RXD  17280   // [64][20] f32: x_dbl row-major
#define LDSW 18560

#define SELH 0x05040100u
#define SELL 0x07060302u

// ---------------- helpers ----------------------------------------------------
__device__ __forceinline__ unsigned bfhi(float x) {  // RNE f32->bf16 (as u32)
  unsigned u = __float_as_uint(x);
  return (u + 0x7FFF + ((u >> 16) & 1)) >> 16;
}
__device__ __forceinline__ unsigned packsplit(float x) {  // (lo<<16)|hi
  unsigned hi = bfhi(x);
  float rem = x - __uint_as_float(hi << 16);
  unsigned lo = bfhi(rem);
  return (hi & 0xFFFFu) | (lo << 16);
}
__device__ __forceinline__ float unpacksplit(unsigned u) {
  return __uint_as_float(u << 16) + __uint_as_float(u & 0xFFFF0000u);
}
__device__ __forceinline__ float fsilu(float v) {
  return v * __builtin_amdgcn_rcpf(1.0f + __builtin_amdgcn_exp2f(-LOG2E * v));
}
__device__ __forceinline__ float qsum4(float v) {  // sum over lane quads (DPP)
  int x = __builtin_amdgcn_update_dpp(0, __float_as_int(v), 0xB1, 0xF, 0xF, true);
  v += __int_as_float(x);
  x = __builtin_amdgcn_update_dpp(0, __float_as_int(v), 0x4E, 0xF, 0xF, true);
  v += __int_as_float(x);
  return v;
}
template <int SI>
__device__ __forceinline__ float qbcast(float v) {  // broadcast quad-lane SI
  constexpr int sel = SI | (SI << 2) | (SI << 4) | (SI << 6);
  return __int_as_float(__builtin_amdgcn_update_dpp(0, __float_as_int(v), sel, 0xF, 0xF, true));
}
// XC k-quad permutation (bank-uniform packed reads)
__device__ __forceinline__ int sigq(int qk) { return (qk >> 1) | ((qk & 1) << 2); }
__device__ __forceinline__ int kpos(int k, int s) {
  return (k & ~31) + ((((sigq((k >> 2) & 7)) + s) & 7) << 2) + (k & 3);
}
union BU { uint4 q; bf16x8 v; unsigned u[4]; };

// ---------------- K0: pre-split weights into MFMA fragment layout -----------
__global__ __launch_bounds__(512) void k_wsplit(const float* __restrict__ Win,
                                                const float* __restrict__ Wout,
                                                const float* __restrict__ Wx,
                                                ushort_t* __restrict__ wsi,
                                                ushort_t* __restrict__ wso,
                                                ushort_t* __restrict__ wsx) {
  int idx = blockIdx.x * 512 + threadIdx.x;
  const float* src;
  ushort_t* dst;
  if (idx < 1024) {
    int row = idx >> 2, kc = idx & 3;
    src = Win + row * 128 + kc * 32;
    dst = wsi + (row * 4 + kc) * 64;
  } else if (idx < 1536) {
    int k = idx - 1024;
    int row = k >> 2, kc = k & 3;
    src = Wout + row * 128 + kc * 32;
    dst = wso + (row * 4 + kc) * 64;
  } else if (idx < 1600) {
    int k = idx - 1536;
    int row = k >> 2, kc = k & 3;
    src = Wx + row * 128 + kc * 32;
    dst = wsx + (row * 4 + kc) * 64;
  } else {
    return;
  }
  for (int g = 0; g < 4; ++g) {
    unsigned hw[4], lw[4];
#pragma unroll
    for (int e2 = 0; e2 < 4; ++e2) {
      float x0 = src[g * 8 + 2 * e2], x1 = src[g * 8 + 2 * e2 + 1];
      unsigned p0 = packsplit(x0), p1 = packsplit(x1);
      hw[e2] = (p0 & 0xFFFFu) | (p1 << 16);
      lw[e2] = (p0 >> 16) | (p1 & 0xFFFF0000u);
    }
    *(uint4*)(dst + (g * 2 + 0) * 8) = make_uint4(hw[0], hw[1], hw[2], hw[3]);
    *(uint4*)(dst + (g * 2 + 1) * 8) = make_uint4(lw[0], lw[1], lw[2], lw[3]);
  }
}

// ---------------- K1: LayerNorm over C + transpose to (B*N, T, C) -----------
__global__ __launch_bounds__(256) void k_ln(const float* __restrict__ x,
                                            const float* __restrict__ gam,
                                            const float* __restrict__ bet,
                                            float* __restrict__ hout) {
  __shared__ float tile[128 * 36];
  __shared__ float ps[8 * 32], pq[8 * 32], mean_s[32], rstd_s[32];
  int bx = blockIdx.x;
  int nt = bx & 7, t = (bx >> 3) & 63, b = bx >> 9;
  int n0 = nt * 32;
  int tid = threadIdx.x;
  const float4* x4 = (const float4*)x;
  for (int it = 0; it < 4; ++it) {
    int idx4 = it * 256 + tid;
    int c = idx4 >> 3, nn4 = idx4 & 7;
    float4 v = x4[((b * C_ + c) * T_ + t) * (N_ / 4) + (n0 >> 2) + nn4];
    *(float4*)&tile[c * 36 + nn4 * 4] = v;
  }
  __syncthreads();
  {
    int nn = tid & 31, cg = tid >> 5;
    float s = 0.f, q = 0.f;
    for (int i = 0; i < 16; ++i) {
      float v = tile[(cg * 16 + i) * 36 + nn];
      s += v; q += v * v;
    }
    ps[cg * 32 + nn] = s; pq[cg * 32 + nn] = q;
  }
  __syncthreads();
  if (tid < 32) {
    float ss = 0.f, qq = 0.f;
    for (int g2 = 0; g2 < 8; ++g2) { ss += ps[g2 * 32 + tid]; qq += pq[g2 * 32 + tid]; }
    float mu = ss * (1.f / 128.f);
    float var = qq * (1.f / 128.f) - mu * mu;
    mean_s[tid] = mu;
    rstd_s[tid] = rsqrtf(var + 1e-5f);
  }
  __syncthreads();
  {
    int c = tid & 127, half = tid >> 7;
    float gm = gam[c], bb = bet[c];
    for (int it = 0; it < 16; ++it) {
      int n = it * 2 + half;
      float v = (tile[c * 36 + n] - mean_s[n]) * rstd_s[n] * gm + bb;
      hout[((b * N_ + n0 + n) * (long)T_ + t) * C_ + c] = v;
    }
  }
}

// ---------------- K2: fused Mamba; ALL weights VGPR-resident ----------------
// __launch_bounds__(512,2): (512,4) makes the allocator clamp to 64 VGPR and
// spill ~0.9 GB/dispatch (r5/r6). (512,2) gives a clean allocation (r4/r7).
__global__ __launch_bounds__(512, 2) void k_mamba(
    float* ws,                          // (B*N, T, C) in-place H -> y
    const ushort_t* __restrict__ wsi,   // pre-split Win fragments
    const ushort_t* __restrict__ wso,   // pre-split Wout fragments
    const ushort_t* __restrict__ wsx,   // pre-split Wx fragments
    const float* __restrict__ convw,    // (3,1,128)
    const float* __restrict__ convb,    // (128)
    const float* __restrict__ Wdt,      // (128,8)
    const float* __restrict__ bdt,      // (128)
    const float* __restrict__ Alog,     // (128,4)
    const float* __restrict__ Dp)       // (128)
{
  extern __shared__ float L[];
  unsigned* Li = (unsigned*)L;
  ushort_t* Ls = (ushort_t*)L;
  int tid = threadIdx.x;
  int lane = tid & 63;
  int w = tid >> 6;                 // wave 0..7
  int r16 = lane & 15, g = lane >> 4;
  const uint4* wsi4 = (const uint4*)wsi;
  const uint4* wso4 = (const uint4*)wso;
  const uint4* wsx4 = (const uint4*)wsx;

  // ---- persistent weight fragments: in_proj hi+lo, out_proj hi+lo (96 VGPR)
  uint4 wih[2][4], wil[2][4], woh[4], wol[4];
#pragma unroll
  for (int ci = 0; ci < 2; ++ci)
#pragma unroll
    for (int kc = 0; kc < 4; ++kc) {
      int cb = ((w * 32 + ci * 16 + r16) * 4 + kc) * 8 + g * 2;
      wih[ci][kc] = wsi4[cb];
      wil[ci][kc] = wsi4[cb + 1];
    }
#pragma unroll
  for (int kc = 0; kc < 4; ++kc) {
    int cb = ((w * 16 + r16) * 4 + kc) * 8 + g * 2;
    woh[kc] = wso4[cb];
    wol[kc] = wso4[cb + 1];
  }

  // ---- per-thread constants ----
  int dc = tid & 127;                                 // conv role
  float cw0 = convw[dc], cw1 = convw[128 + dc], cw2 = convw[256 + dc];
  float cbv = convb[dc];
  int ds = tid >> 2, ss = tid & 3;                    // scan role
  float4 wdta = *(const float4*)&Wdt[ds * 8];
  float4 wdtb = *(const float4*)&Wdt[ds * 8 + 4];
  float bd = bdt[ds];
  float As2 = -expf(Alog[ds * 4 + ss]) * LOG2E;
  float Dd = Dp[ds];
  int kc_d = (ds & ~31) + (ds & 3);                   // scan xc addr pieces
  int qs_d = sigq((ds >> 2) & 7);

  for (int iseq = 0; iseq < NSEQ; ++iseq) {
    float* hseq = ws + ((long)blockIdx.x * NSEQ + iseq) * (T_ * C_);

    // ---- P0: stage H into split hi/lo regions (no perms needed in P1) ----
    {
      const float4* h4 = (const float4*)hseq;
      int ts = tid >> 3, kg = tid & 7;
      unsigned hw[8], lw[8];
#pragma unroll
      for (int q = 0; q < 4; ++q) {
        float4 v = h4[ts * 32 + kg * 4 + q];
        unsigned h0 = bfhi(v.x), h1 = bfhi(v.y), h2 = bfhi(v.z), h3 = bfhi(v.w);
        hw[2 * q]     = h0 | (h1 << 16);
        hw[2 * q + 1] = h2 | (h3 << 16);
        float r0 = v.x - __uint_as_float(h0 << 16);
        float r1 = v.y - __uint_as_float(h1 << 16);
        float r2 = v.z - __uint_as_float(h2 << 16);
        float r3 = v.w - __uint_as_float(h3 << 16);
        lw[2 * q]     = bfhi(r0) | (bfhi(r1) << 16);
        lw[2 * q + 1] = bfhi(r2) | (bfhi(r3) << 16);
      }
      *(uint4*)&Li[RH + ts * 68 + kg * 8]     = make_uint4(hw[0], hw[1], hw[2], hw[3]);
      *(uint4*)&Li[RH + ts * 68 + kg * 8 + 4] = make_uint4(hw[4], hw[5], hw[6], hw[7]);
      *(uint4*)&Li[RL + ts * 68 + kg * 8]     = make_uint4(lw[0], lw[1], lw[2], lw[3]);
      *(uint4*)&Li[RL + ts * 68 + kg * 8 + 4] = make_uint4(lw[4], lw[5], lw[6], lw[7]);
    }
    __syncthreads();

    // ---- P1: in_proj xz(64x256) = H @ Win^T (all weights in VGPR) ----
    f32x4 acc[4][2];
#pragma unroll
    for (int rt = 0; rt < 4; ++rt)
#pragma unroll
      for (int ci = 0; ci < 2; ++ci) acc[rt][ci] = (f32x4){0.f, 0.f, 0.f, 0.f};
#pragma unroll
    for (int kc = 0; kc < 4; ++kc) {
      BU bh0, bl0, bh1, bl1;
      bh0.q = wih[0][kc]; bl0.q = wil[0][kc];
      bh1.q = wih[1][kc]; bl1.q = wil[1][kc];
#pragma unroll
      for (int rt = 0; rt < 4; ++rt) {
        int row = rt * 16 + r16;
        BU ah, al;
        ah.q = *(const uint4*)&Li[RH + row * 68 + kc * 16 + g * 4];
        al.q = *(const uint4*)&Li[RL + row * 68 + kc * 16 + g * 4];
        acc[rt][0] = __builtin_amdgcn_mfma_f32_16x16x32_bf16(al.v, bh0.v, acc[rt][0], 0, 0, 0);
        acc[rt][0] = __builtin_amdgcn_mfma_f32_16x16x32_bf16(ah.v, bl0.v, acc[rt][0], 0, 0, 0);
        acc[rt][0] = __builtin_amdgcn_mfma_f32_16x16x32_bf16(ah.v, bh0.v, acc[rt][0], 0, 0, 0);
        acc[rt][1] = __builtin_amdgcn_mfma_f32_16x16x32_bf16(al.v, bh1.v, acc[rt][1], 0, 0, 0);
        acc[rt][1] = __builtin_amdgcn_mfma_f32_16x16x32_bf16(ah.v, bl1.v, acc[rt][1], 0, 0, 0);
        acc[rt][1] = __builtin_amdgcn_mfma_f32_16x16x32_bf16(ah.v, bh1.v, acc[rt][1], 0, 0, 0);
      }
    }
    __syncthreads();   // all H reads done before regions are overwritten

    // ---- P2: scatter: waves 0-3 -> x f32 [t][132] over RH/RL region start;
    //          waves 4-7 -> silu(z) [d][67] in R1.
    //          NOTE: x f32 region [64][132] (8448 w) occupies RH+RL (8704 w).
    {
      int dl0 = (w & 3) * 32;
      if (w < 4) {
#pragma unroll
        for (int rt = 0; rt < 4; ++rt)
#pragma unroll
          for (int ci = 0; ci < 2; ++ci)
#pragma unroll
            for (int r = 0; r < 4; ++r)
              L[(rt * 16 + g * 4 + r) * 132 + dl0 + ci * 16 + r16] = acc[rt][ci][r];
      } else {
#pragma unroll
        for (int rt = 0; rt < 4; ++rt)
#pragma unroll
          for (int ci = 0; ci < 2; ++ci)
#pragma unroll
            for (int r = 0; r < 4; ++r)
              L[R1 + (dl0 + ci * 16 + r16) * 67 + rt * 16 + g * 4 + r] = fsilu(acc[rt][ci][r]);
      }
    }
    __syncthreads();

    // ---- P3: causal conv(3) + SiLU; result packed XC into RXD-adjacent?? no:
    //          packed XC goes back into the SAME [t][132] region (sigma slots)
    {
      int tq = tid >> 7;
      int t0 = tq * 16;
      float xin[18];
#pragma unroll
      for (int ii = 0; ii < 18; ++ii) {
        int t = t0 - 2 + ii;
        xin[ii] = (t < 0) ? 0.f : L[t * 132 + dc];
      }
      __syncthreads();   // all pre-conv reads done before overwrite
#pragma unroll
      for (int ii = 0; ii < 16; ++ii) {
        int t = t0 + ii;
        float v = fmaf(cw2, xin[ii + 2], fmaf(cw1, xin[ii + 1], fmaf(cw0, xin[ii], cbv)));
        Li[t * 132 + kpos(dc, t & 7)] = packsplit(fsilu(v));
      }
    }
    __syncthreads();

    // ---- P4: x_proj x_dbl(64x16) = XC @ Wx^T via MFMA (waves 0-3) ----
    if (w < 4) {
      int s = r16 & 7;
      int slotA = (g + s) & 7, slotB = (g + 4 + s) & 7;
      f32x4 o = (f32x4){0.f, 0.f, 0.f, 0.f};
#pragma unroll
      for (int kc = 0; kc < 4; ++kc) {
        int cb = (r16 * 4 + kc) * 8 + g * 2;
        BU bh, bl;
        bh.q = wsx4[cb];
        bl.q = wsx4[cb + 1];
        int base = (w * 16 + r16) * 132 + kc * 32;
        uint4 wa = *(const uint4*)&Li[base + slotA * 4];
        uint4 wb = *(const uint4*)&Li[base + slotB * 4];
        BU ah, al;
        ah.u[0] = __builtin_amdgcn_perm(wa.y, wa.x, SELH);
        ah.u[1] = __builtin_amdgcn_perm(wa.w, wa.z, SELH);
        ah.u[2] = __builtin_amdgcn_perm(wb.y, wb.x, SELH);
        ah.u[3] = __builtin_amdgcn_perm(wb.w, wb.z, SELH);
        al.u[0] = __builtin_amdgcn_perm(wa.y, wa.x, SELL);
        al.u[1] = __builtin_amdgcn_perm(wa.w, wa.z, SELL);
        al.u[2] = __builtin_amdgcn_perm(wb.y, wb.x, SELL);
        al.u[3] = __builtin_amdgcn_perm(wb.w, wb.z, SELL);
        o = __builtin_amdgcn_mfma_f32_16x16x32_bf16(al.v, bh.v, o, 0, 0, 0);
        o = __builtin_amdgcn_mfma_f32_16x16x32_bf16(ah.v, bl.v, o, 0, 0, 0);
        o = __builtin_amdgcn_mfma_f32_16x16x32_bf16(ah.v, bh.v, o, 0, 0, 0);
      }
#pragma unroll
      for (int q = 0; q < 4; ++q)
        L[RXD + (w * 16 + g * 4 + q) * 20 + r16] = o[q];
    }
    __syncthreads();

    // ---- P5: selective scan; Y written SPLIT to RH/RL tails (u16 stores) ----
    // Y region: RH/RL rows [t][68] reused (dead since P1; x f32 was consumed by
    // conv; packed XC lives in the same [t][132] area as the sigma slots --
    // note [64][132]=8448 <= 8704, and Y-hi/Y-lo go to word rows t*68 which
    // overlap the XC area. To avoid aliasing, Y goes to R1+ area? NO --
    // silu(z) (R1) is still being read. Instead Y-hi/Y-lo are placed in the
    // TAIL: RXD+1280 .. +1280+8704 doesn't exist. So: Y overwrites the packed
    // XC cell (as before, r7 scheme) -- packed single-u32 write, P6 reads with
    // perms. (Perm elimination in P6 deferred; aliasing-free requires more LDS.)
    {
      float hsv = 0.f;
#pragma unroll
      for (int tb = 0; tb < 16; ++tb) {
        int tme = tb * 4 + ss;                        // this lane's dt timestep
        const float* xr = &L[RXD + tme * 20];
        float4 xa = *(const float4*)xr;
        float4 xb = *(const float4*)(xr + 4);
        float dot = bd;
        dot = fmaf(xa.x, wdta.x, dot); dot = fmaf(xa.y, wdta.y, dot);
        dot = fmaf(xa.z, wdta.z, dot); dot = fmaf(xa.w, wdta.w, dot);
        dot = fmaf(xb.x, wdtb.x, dot); dot = fmaf(xb.y, wdtb.y, dot);
        dot = fmaf(xb.z, wdtb.z, dot); dot = fmaf(xb.w, wdtb.w, dot);
        float e = __builtin_amdgcn_exp2f(dot * LOG2E);
        float sp = LN2 * __builtin_amdgcn_logf(1.0f + e);
        float dtme = (dot > 20.f) ? dot : sp;         // softplus(own t)

#define SCANSTEP(SI)                                                          \
        {                                                                     \
          int t = tb * 4 + SI;                                                \
          float dtv = qbcast<SI>(dtme);                                       \
          float Bs = L[RXD + t * 20 + 8 + ss];                                \
          float Cs = L[RXD + t * 20 + 12 + ss];                               \
          int xoff = t * 132 + kc_d + (((qs_d + (t & 7)) & 7) << 2);          \
          float xcv = unpacksplit(Li[xoff]);                                  \
          float dA = __builtin_amdgcn_exp2f(dtv * As2);                       \
          hsv = fmaf(hsv, dA, dtv * xcv * Bs);                                \
          float y = qsum4(hsv * Cs);                                          \
          if (SI == ss) {                                                     \
            y = fmaf(xcv, Dd, y);                                             \
            y *= L[R1 + ds * 67 + t];                                         \
            Li[xoff] = packsplit(y);                                          \
          }                                                                   \
        }
        SCANSTEP(0)
        SCANSTEP(1)
        SCANSTEP(2)
        SCANSTEP(3)
#undef SCANSTEP
      }
    }
    __syncthreads();

    // ---- P6: out_proj out(64x128) = Y @ Wout^T (weights in VGPR) ----
    {
      int s = r16 & 7;
      int slotA = (g + s) & 7, slotB = (g + 4 + s) & 7;
      f32x4 o[4];
#pragma unroll
      for (int rt = 0; rt < 4; ++rt) o[rt] = (f32x4){0.f, 0.f, 0.f, 0.f};
#pragma unroll
      for (int kc = 0; kc < 4; ++kc) {
        BU bh, bl;
        bh.q = woh[kc];
        bl.q = wol[kc];
#pragma unroll
        for (int rt = 0; rt < 4; ++rt) {
          int base = (rt * 16 + r16) * 132 + kc * 32;
          uint4 wa = *(const uint4*)&Li[base + slotA * 4];
          uint4 wb = *(const uint4*)&Li[base + slotB * 4];
          BU ah, al;
          ah.u[0] = __builtin_amdgcn_perm(wa.y, wa.x, SELH);
          ah.u[1] = __builtin_amdgcn_perm(wa.w, wa.z, SELH);
          ah.u[2] = __builtin_amdgcn_perm(wb.y, wb.x, SELH);
          ah.u[3] = __builtin_amdgcn_perm(wb.w, wb.z, SELH);
          al.u[0] = __builtin_amdgcn_perm(wa.y, wa.x, SELL);
          al.u[1] = __builtin_amdgcn_perm(wa.w, wa.z, SELL);
          al.u[2] = __builtin_amdgcn_perm(wb.y, wb.x, SELL);
          al.u[3] = __builtin_amdgcn_perm(wb.w, wb.z, SELL);
          o[rt] = __builtin_amdgcn_mfma_f32_16x16x32_bf16(al.v, bh.v, o[rt], 0, 0, 0);
          o[rt] = __builtin_amdgcn_mfma_f32_16x16x32_bf16(ah.v, bl.v, o[rt], 0, 0, 0);
          o[rt] = __builtin_amdgcn_mfma_f32_16x16x32_bf16(ah.v, bh.v, o[rt], 0, 0, 0);
        }
      }
#pragma unroll
      for (int rt = 0; rt < 4; ++rt)
#pragma unroll
        for (int r = 0; r < 4; ++r)
          hseq[(rt * 16 + g * 4 + r) * C_ + w * 16 + r16] = o[rt][r];
    }
    __syncthreads();   // LDS reuse next sequence
  }
}

// ---------------- K3: transpose (B*N,T,C) -> (B,C,T,N) ----------------------
__global__ __launch_bounds__(256) void k_out_tr(const float* __restrict__ ws_y,
                                                float* __restrict__ out) {
  __shared__ float tile[32 * 132];
  int bx = blockIdx.x;
  int nt = bx & 7, t = (bx >> 3) & 63, b = bx >> 9;
  int n0 = nt * 32;
  int tid = threadIdx.x;
  const float4* y4 = (const float4*)ws_y;
  for (int it = 0; it < 4; ++it) {
    int idx4 = it * 256 + tid;
    int nn = idx4 >> 5, c4 = idx4 & 31;
    float4 v = y4[((b * N_ + n0 + nn) * (long)T_ + t) * (C_ / 4) + c4];
    *(float4*)&tile[nn * 132 + c4 * 4] = v;
  }
  __syncthreads();
  int nn = tid & 31, cg = tid >> 5;
  for (int i = 0; i < 16; ++i) {
    int c = cg * 16 + i;
    out[((b * C_ + c) * (long)T_ + t) * N_ + n0 + nn] = tile[nn * 132 + c];
  }
}

extern "C" void kernel_launch(void* const* d_in, const int* in_sizes, int n_in,
                              void* d_out, int out_size, void* d_ws, size_t ws_size,
                              hipStream_t stream) {
  const float* x    = (const float*)d_in[0];
  const float* gam  = (const float*)d_in[1];
  const float* bet  = (const float*)d_in[2];
  const float* Win  = (const float*)d_in[3];
  const float* cw   = (const float*)d_in[4];
  const float* cb   = (const float*)d_in[5];
  const float* Wx   = (const float*)d_in[6];
  const float* Wdt  = (const float*)d_in[7];
  const float* bdt  = (const float*)d_in[8];
  const float* Alog = (const float*)d_in[9];
  const float* Dp   = (const float*)d_in[10];
  const float* Wout = (const float*)d_in[11];
  float* out = (float*)d_out;
  float* ws  = (float*)d_ws;   // 64 MiB: (B*N, T, C) fp32, in-place H -> y

  // split-weight storage: ws tail if it fits, else scribble d_out
  const size_t HBYTES = 67108864ull;                      // 64 MiB
  const size_t WBYTES = 131072ull + 65536ull + 8192ull;   // Win + Wout + Wx splits
  char* wtail;
  if (ws_size >= HBYTES + WBYTES) wtail = (char*)d_ws + HBYTES;
  else                            wtail = (char*)d_out;
  ushort_t* wsi = (ushort_t*)wtail;
  ushort_t* wso = (ushort_t*)(wtail + 131072);
  ushort_t* wsx = (ushort_t*)(wtail + 131072 + 65536);

  (void)hipFuncSetAttribute((const void*)k_mamba,
                            hipFuncAttributeMaxDynamicSharedMemorySize,
                            LDSW * 4);

  k_wsplit<<<4, 512, 0, stream>>>(Win, Wout, Wx, wsi, wso, wsx);
  k_ln<<<4096, 256, 0, stream>>>(x, gam, bet, ws);
  k_mamba<<<2048 / NSEQ, 512, LDSW * 4, stream>>>(ws, wsi, wso, wsx, cw, cb,
                                                  Wdt, bdt, Alog, Dp);
  k_out_tr<<<4096, 256, 0, stream>>>(ws, out);
}

// Round 9
// 228.311 us; speedup vs baseline: 1.9488x; 1.9488x over previous
//
#include <hip/hip_runtime.h>
#include <math.h>

#define B_   8
#define C_   128
#define T_   64
#define N_   256
#define NSEQ 4

typedef __attribute__((ext_vector_type(8))) short bf16x8;
typedef __attribute__((ext_vector_type(4))) float f32x4;
typedef unsigned short ushort_t;

#define LOG2E 1.4426950408889634f
#define LN2   0.6931471805599453f

// ---- LDS word layout (18304 words = 73216 B -> 2 blocks/CU at VGPR<=128) ----
#define R0   0       // [64][132] u32: packed H -> f32 xz(x) -> packed XC -> packed Y
#define R1   8448    // [128][67] f32: silu(z), [d][t] odd-stride
#define RXD  17024   // [64][20] f32: x_dbl interleaved: slot s*4 = {xd2s, xd2s+1, Bs, Cs}
#define LDSW 18304

#define SELH 0x05040100u
#define SELL 0x07060302u

// ---------------- helpers ----------------------------------------------------
__device__ __forceinline__ unsigned bfhi(float x) {  // RNE f32->bf16 (as u16)
  unsigned u = __float_as_uint(x);
  return (u + 0x7FFF + ((u >> 16) & 1)) >> 16;
}
__device__ __forceinline__ unsigned packsplit(float x) {  // (lo<<16)|hi
  unsigned hi = bfhi(x);
  float rem = x - __uint_as_float(hi << 16);
  unsigned lo = bfhi(rem);
  return (hi & 0xFFFFu) | (lo << 16);
}
__device__ __forceinline__ float unpacksplit(unsigned u) {
  return __uint_as_float(u << 16) + __uint_as_float(u & 0xFFFF0000u);
}
__device__ __forceinline__ float fsilu(float v) {
  return v * __builtin_amdgcn_rcpf(1.0f + __builtin_amdgcn_exp2f(-LOG2E * v));
}
__device__ __forceinline__ float qsum4(float v) {  // sum over lane quads (DPP)
  int x = __builtin_amdgcn_update_dpp(0, __float_as_int(v), 0xB1, 0xF, 0xF, true);
  v += __int_as_float(x);
  x = __builtin_amdgcn_update_dpp(0, __float_as_int(v), 0x4E, 0xF, 0xF, true);
  v += __int_as_float(x);
  return v;
}
// k-quad storage permutation: quad qk (0..7 within 32-elem kc-block) stored at
// slot (sigq(qk) + (row&7)) & 7 ; sigq = 0,4,1,5,2,6,3,7 (bank-uniform reads)
__device__ __forceinline__ int sigq(int qk) { return (qk >> 1) | ((qk & 1) << 2); }
__device__ __forceinline__ int kpos(int k, int s) {  // word offset of element k in row
  return (k & ~31) + ((((sigq((k >> 2) & 7)) + s) & 7) << 2) + (k & 3);
}
union BU { uint4 q; bf16x8 v; unsigned u[4]; };

// ---------------- K0: pre-split weights into MFMA fragment layout -----------
__global__ __launch_bounds__(512) void k_wsplit(const float* __restrict__ Win,
                                                const float* __restrict__ Wout,
                                                const float* __restrict__ Wx,
                                                ushort_t* __restrict__ wsi,
                                                ushort_t* __restrict__ wso,
                                                ushort_t* __restrict__ wsx) {
  int idx = blockIdx.x * 512 + threadIdx.x;
  const float* src;
  ushort_t* dst;
  if (idx < 1024) {
    int row = idx >> 2, kc = idx & 3;
    src = Win + row * 128 + kc * 32;
    dst = wsi + (row * 4 + kc) * 64;
  } else if (idx < 1536) {
    int k = idx - 1024;
    int row = k >> 2, kc = k & 3;
    src = Wout + row * 128 + kc * 32;
    dst = wso + (row * 4 + kc) * 64;
  } else if (idx < 1600) {
    int k = idx - 1536;
    int row = k >> 2, kc = k & 3;
    src = Wx + row * 128 + kc * 32;
    dst = wsx + (row * 4 + kc) * 64;
  } else {
    return;
  }
  for (int g = 0; g < 4; ++g) {
    unsigned hw[4], lw[4];
#pragma unroll
    for (int e2 = 0; e2 < 4; ++e2) {
      float x0 = src[g * 8 + 2 * e2], x1 = src[g * 8 + 2 * e2 + 1];
      unsigned p0 = packsplit(x0), p1 = packsplit(x1);
      hw[e2] = (p0 & 0xFFFFu) | (p1 << 16);
      lw[e2] = (p0 >> 16) | (p1 & 0xFFFF0000u);
    }
    *(uint4*)(dst + (g * 2 + 0) * 8) = make_uint4(hw[0], hw[1], hw[2], hw[3]);
    *(uint4*)(dst + (g * 2 + 1) * 8) = make_uint4(lw[0], lw[1], lw[2], lw[3]);
  }
}

// ---------------- K1: LayerNorm over C + transpose to (B*N, T, C) -----------
__global__ __launch_bounds__(256) void k_ln(const float* __restrict__ x,
                                            const float* __restrict__ gam,
                                            const float* __restrict__ bet,
                                            float* __restrict__ hout) {
  __shared__ float tile[128 * 36];
  __shared__ float ps[8 * 32], pq[8 * 32], mean_s[32], rstd_s[32];
  int bx = blockIdx.x;
  int nt = bx & 7, t = (bx >> 3) & 63, b = bx >> 9;
  int n0 = nt * 32;
  int tid = threadIdx.x;
  const float4* x4 = (const float4*)x;
  for (int it = 0; it < 4; ++it) {
    int idx4 = it * 256 + tid;
    int c = idx4 >> 3, nn4 = idx4 & 7;
    float4 v = x4[((b * C_ + c) * T_ + t) * (N_ / 4) + (n0 >> 2) + nn4];
    *(float4*)&tile[c * 36 + nn4 * 4] = v;
  }
  __syncthreads();
  {
    int nn = tid & 31, cg = tid >> 5;
    float s = 0.f, q = 0.f;
    for (int i = 0; i < 16; ++i) {
      float v = tile[(cg * 16 + i) * 36 + nn];
      s += v; q += v * v;
    }
    ps[cg * 32 + nn] = s; pq[cg * 32 + nn] = q;
  }
  __syncthreads();
  if (tid < 32) {
    float ss = 0.f, qq = 0.f;
    for (int g2 = 0; g2 < 8; ++g2) { ss += ps[g2 * 32 + tid]; qq += pq[g2 * 32 + tid]; }
    float mu = ss * (1.f / 128.f);
    float var = qq * (1.f / 128.f) - mu * mu;
    mean_s[tid] = mu;
    rstd_s[tid] = rsqrtf(var + 1e-5f);
  }
  __syncthreads();
  {
    int c = tid & 127, half = tid >> 7;
    float gm = gam[c], bb = bet[c];
    for (int it = 0; it < 16; ++it) {
      int n = it * 2 + half;
      float v = (tile[c * 36 + n] - mean_s[n]) * rstd_s[n] * gm + bb;
      hout[((b * N_ + n0 + n) * (long)T_ + t) * C_ + c] = v;
    }
  }
}

// ---------------- K2: fused Mamba, NSEQ seq/block, reg weights ---------------
// __launch_bounds__(512,2): with min_waves=4 the allocator clamps to 64 VGPR
// and spills ~0.9 GB/dispatch (r5/r6). With min_waves=2 and THIS P1/P6 code
// shape it allocates 128 VGPR cleanly (r4) -> HW can co-schedule 2 blocks/CU
// since LDS is 73 KB.
__global__ __launch_bounds__(512, 2) void k_mamba(
    float* ws,                          // (B*N, T, C) in-place H -> y
    const ushort_t* __restrict__ wsi,   // pre-split Win fragments
    const ushort_t* __restrict__ wso,   // pre-split Wout fragments
    const ushort_t* __restrict__ wsx,   // pre-split Wx fragments
    const float* __restrict__ convw,    // (3,1,128)
    const float* __restrict__ convb,    // (128)
    const float* __restrict__ Wdt,      // (128,8)
    const float* __restrict__ bdt,      // (128)
    const float* __restrict__ Alog,     // (128,4)
    const float* __restrict__ Dp)       // (128)
{
  extern __shared__ float L[];
  unsigned* Li = (unsigned*)L;
  int tid = threadIdx.x;
  int lane = tid & 63;
  int w = tid >> 6;                 // wave 0..7
  int r16 = lane & 15, g = lane >> 4;
  const uint4* wsi4 = (const uint4*)wsi;
  const uint4* wso4 = (const uint4*)wso;
  const uint4* wsx4 = (const uint4*)wsx;

  // ---- persistent weight fragments (VGPR-resident across NSEQ) ----
  uint4 wih[2][4], wil[2][4], woh[4], wol[4];
#pragma unroll
  for (int ci = 0; ci < 2; ++ci)
#pragma unroll
    for (int kc = 0; kc < 4; ++kc) {
      int cb = ((w * 32 + ci * 16 + r16) * 4 + kc) * 8 + g * 2;
      wih[ci][kc] = wsi4[cb];
      wil[ci][kc] = wsi4[cb + 1];
    }
#pragma unroll
  for (int kc = 0; kc < 4; ++kc) {
    int cb = ((w * 16 + r16) * 4 + kc) * 8 + g * 2;
    woh[kc] = wso4[cb];
    wol[kc] = wso4[cb + 1];
  }
  // ---- per-thread constants ----
  int dc = tid & 127;                                 // conv role
  float cw0 = convw[dc], cw1 = convw[128 + dc], cw2 = convw[256 + dc];
  float cbv = convb[dc];
  int ds = tid >> 2, ss = tid & 3;                    // scan role
  float wA = Wdt[ds * 8 + 2 * ss], wB = Wdt[ds * 8 + 2 * ss + 1];
  float bd = bdt[ds];
  float As2 = -expf(Alog[ds * 4 + ss]) * LOG2E;
  float Dd = Dp[ds];
  int kc_d = (ds & ~31) + (ds & 3);                   // scan xc addr pieces
  int qs_d = sigq((ds >> 2) & 7);

  for (int iseq = 0; iseq < NSEQ; ++iseq) {
    float* hseq = ws + ((long)blockIdx.x * NSEQ + iseq) * (T_ * C_);

    // ---- P0: stage H packed split-bf16, sigma-swizzled rows ----
    {
      const float4* h4 = (const float4*)hseq;
      int ts = tid >> 3, kg = tid & 7;
      int s = ts & 7;
      int slot = (sigq(kg) + s) & 7;
#pragma unroll
      for (int q = 0; q < 4; ++q) {
        float4 v = h4[ts * 32 + kg + 8 * q];
        uint4 pw = make_uint4(packsplit(v.x), packsplit(v.y), packsplit(v.z), packsplit(v.w));
        *(uint4*)&Li[R0 + ts * 132 + q * 32 + slot * 4] = pw;
      }
    }
    __syncthreads();

    // ---- P1: in_proj xz(64x256) = H @ Win^T ----
    f32x4 acc[4][2];
#pragma unroll
    for (int rt = 0; rt < 4; ++rt)
#pragma unroll
      for (int ci = 0; ci < 2; ++ci) acc[rt][ci] = (f32x4){0.f, 0.f, 0.f, 0.f};
    {
      int s = r16 & 7;
      int slotA = (g + s) & 7, slotB = (g + 4 + s) & 7;
#pragma unroll
      for (int kc = 0; kc < 4; ++kc) {
#pragma unroll
        for (int rt = 0; rt < 4; ++rt) {
          int base = R0 + (rt * 16 + r16) * 132 + kc * 32;
          uint4 wa = *(const uint4*)&Li[base + slotA * 4];
          uint4 wb = *(const uint4*)&Li[base + slotB * 4];
          BU ah, al;
          ah.u[0] = __builtin_amdgcn_perm(wa.y, wa.x, SELH);
          ah.u[1] = __builtin_amdgcn_perm(wa.w, wa.z, SELH);
          ah.u[2] = __builtin_amdgcn_perm(wb.y, wb.x, SELH);
          ah.u[3] = __builtin_amdgcn_perm(wb.w, wb.z, SELH);
          al.u[0] = __builtin_amdgcn_perm(wa.y, wa.x, SELL);
          al.u[1] = __builtin_amdgcn_perm(wa.w, wa.z, SELL);
          al.u[2] = __builtin_amdgcn_perm(wb.y, wb.x, SELL);
          al.u[3] = __builtin_amdgcn_perm(wb.w, wb.z, SELL);
#pragma unroll
          for (int ci = 0; ci < 2; ++ci) {
            BU bh, bl;
            bh.q = wih[ci][kc];
            bl.q = wil[ci][kc];
            acc[rt][ci] = __builtin_amdgcn_mfma_f32_16x16x32_bf16(al.v, bh.v, acc[rt][ci], 0, 0, 0);
            acc[rt][ci] = __builtin_amdgcn_mfma_f32_16x16x32_bf16(ah.v, bl.v, acc[rt][ci], 0, 0, 0);
            acc[rt][ci] = __builtin_amdgcn_mfma_f32_16x16x32_bf16(ah.v, bh.v, acc[rt][ci], 0, 0, 0);
          }
        }
      }
    }
    __syncthreads();   // all H reads done before R0 overwrite

    // ---- P2: scatter: waves 0-3 -> x f32 [t][132] (R0); 4-7 -> silu(z) [d][67]
    {
      int dl0 = (w & 3) * 32;
      if (w < 4) {
#pragma unroll
        for (int rt = 0; rt < 4; ++rt)
#pragma unroll
          for (int ci = 0; ci < 2; ++ci)
#pragma unroll
            for (int r = 0; r < 4; ++r)
              L[R0 + (rt * 16 + g * 4 + r) * 132 + dl0 + ci * 16 + r16] = acc[rt][ci][r];
      } else {
#pragma unroll
        for (int rt = 0; rt < 4; ++rt)
#pragma unroll
          for (int ci = 0; ci < 2; ++ci)
#pragma unroll
            for (int r = 0; r < 4; ++r)
              L[R1 + (dl0 + ci * 16 + r16) * 67 + rt * 16 + g * 4 + r] = fsilu(acc[rt][ci][r]);
      }
    }
    __syncthreads();

    // ---- P3: causal conv(3) + SiLU; write packed XC (sigma slots) ----
    {
      int tq = tid >> 7;
      int t0 = tq * 16;
      float xin[18];
#pragma unroll
      for (int ii = 0; ii < 18; ++ii) {
        int t = t0 - 2 + ii;
        xin[ii] = (t < 0) ? 0.f : L[R0 + t * 132 + dc];
      }
      __syncthreads();   // all pre-conv reads done before overwrite
#pragma unroll
      for (int ii = 0; ii < 16; ++ii) {
        int t = t0 + ii;
        float v = fmaf(cw2, xin[ii + 2], fmaf(cw1, xin[ii + 1], fmaf(cw0, xin[ii], cbv)));
        Li[R0 + t * 132 + kpos(dc, t & 7)] = packsplit(fsilu(v));
      }
    }
    __syncthreads();

    // ---- P4: x_proj x_dbl(64x16) = XC @ Wx^T via MFMA (waves 0-3) ----
    if (w < 4) {
      int s = r16 & 7;
      int slotA = (g + s) & 7, slotB = (g + 4 + s) & 7;
      f32x4 o = (f32x4){0.f, 0.f, 0.f, 0.f};
#pragma unroll
      for (int kc = 0; kc < 4; ++kc) {
        int cb = (r16 * 4 + kc) * 8 + g * 2;
        BU bh, bl;
        bh.q = wsx4[cb];
        bl.q = wsx4[cb + 1];
        int base = R0 + (w * 16 + r16) * 132 + kc * 32;
        uint4 wa = *(const uint4*)&Li[base + slotA * 4];
        uint4 wb = *(const uint4*)&Li[base + slotB * 4];
        BU ah, al;
        ah.u[0] = __builtin_amdgcn_perm(wa.y, wa.x, SELH);
        ah.u[1] = __builtin_amdgcn_perm(wa.w, wa.z, SELH);
        ah.u[2] = __builtin_amdgcn_perm(wb.y, wb.x, SELH);
        ah.u[3] = __builtin_amdgcn_perm(wb.w, wb.z, SELH);
        al.u[0] = __builtin_amdgcn_perm(wa.y, wa.x, SELL);
        al.u[1] = __builtin_amdgcn_perm(wa.w, wa.z, SELL);
        al.u[2] = __builtin_amdgcn_perm(wb.y, wb.x, SELL);
        al.u[3] = __builtin_amdgcn_perm(wb.w, wb.z, SELL);
        o = __builtin_amdgcn_mfma_f32_16x16x32_bf16(al.v, bh.v, o, 0, 0, 0);
        o = __builtin_amdgcn_mfma_f32_16x16x32_bf16(ah.v, bl.v, o, 0, 0, 0);
        o = __builtin_amdgcn_mfma_f32_16x16x32_bf16(ah.v, bh.v, o, 0, 0, 0);
      }
      int p = (r16 < 8) ? ((r16 >> 1) * 4 + (r16 & 1))
                        : (r16 < 12 ? (r16 - 8) * 4 + 2 : (r16 - 12) * 4 + 3);
#pragma unroll
      for (int q = 0; q < 4; ++q)
        L[RXD + (w * 16 + g * 4 + q) * 20 + p] = o[q];
    }
    __syncthreads();

    // ---- P5: selective scan, 128 d x 4 s; packed Y over packed XC ----
    {
      float h = 0.f;
#pragma unroll 8
      for (int t = 0; t < 64; ++t) {
        float4 xd = *(const float4*)&L[RXD + t * 20 + ss * 4];
        float dtv = qsum4(fmaf(xd.x, wA, xd.y * wB)) + bd;
        float e = __builtin_amdgcn_exp2f(dtv * LOG2E);
        float sp = LN2 * __builtin_amdgcn_logf(1.0f + e);
        dtv = (dtv > 20.f) ? dtv : sp;               // softplus
        int xoff = R0 + t * 132 + kc_d + (((qs_d + (t & 7)) & 7) << 2);
        float xcv = unpacksplit(Li[xoff]);
        float dA = __builtin_amdgcn_exp2f(dtv * As2);
        h = fmaf(h, dA, dtv * xcv * xd.z);
        float y = qsum4(h * xd.w);                   // sum over 4 states
        if ((t & 3) == ss) {
          y = fmaf(xcv, Dd, y);
          y *= L[R1 + ds * 67 + t];                  // silu(z) f32
          Li[xoff] = packsplit(y);                   // Y over dead XC cell
        }
      }
    }
    __syncthreads();

    // ---- P6: out_proj out(64x128) = Y @ Wout^T ----
    {
      int s = r16 & 7;
      int slotA = (g + s) & 7, slotB = (g + 4 + s) & 7;
      f32x4 o[4];
#pragma unroll
      for (int rt = 0; rt < 4; ++rt) o[rt] = (f32x4){0.f, 0.f, 0.f, 0.f};
#pragma unroll
      for (int kc = 0; kc < 4; ++kc) {
        BU bh, bl;
        bh.q = woh[kc];
        bl.q = wol[kc];
#pragma unroll
        for (int rt = 0; rt < 4; ++rt) {
          int base = R0 + (rt * 16 + r16) * 132 + kc * 32;
          uint4 wa = *(const uint4*)&Li[base + slotA * 4];
          uint4 wb = *(const uint4*)&Li[base + slotB * 4];
          BU ah, al;
          ah.u[0] = __builtin_amdgcn_perm(wa.y, wa.x, SELH);
          ah.u[1] = __builtin_amdgcn_perm(wa.w, wa.z, SELH);
          ah.u[2] = __builtin_amdgcn_perm(wb.y, wb.x, SELH);
          ah.u[3] = __builtin_amdgcn_perm(wb.w, wb.z, SELH);
          al.u[0] = __builtin_amdgcn_perm(wa.y, wa.x, SELL);
          al.u[1] = __builtin_amdgcn_perm(wa.w, wa.z, SELL);
          al.u[2] = __builtin_amdgcn_perm(wb.y, wb.x, SELL);
          al.u[3] = __builtin_amdgcn_perm(wb.w, wb.z, SELL);
          o[rt] = __builtin_amdgcn_mfma_f32_16x16x32_bf16(al.v, bh.v, o[rt], 0, 0, 0);
          o[rt] = __builtin_amdgcn_mfma_f32_16x16x32_bf16(ah.v, bl.v, o[rt], 0, 0, 0);
          o[rt] = __builtin_amdgcn_mfma_f32_16x16x32_bf16(ah.v, bh.v, o[rt], 0, 0, 0);
        }
      }
#pragma unroll
      for (int rt = 0; rt < 4; ++rt)
#pragma unroll
        for (int r = 0; r < 4; ++r)
          hseq[(rt * 16 + g * 4 + r) * C_ + w * 16 + r16] = o[rt][r];
    }
    __syncthreads();   // LDS reuse next sequence
  }
}

// ---------------- K3: transpose (B*N,T,C) -> (B,C,T,N) ----------------------
__global__ __launch_bounds__(256) void k_out_tr(const float* __restrict__ ws_y,
                                                float* __restrict__ out) {
  __shared__ float tile[32 * 132];
  int bx = blockIdx.x;
  int nt = bx & 7, t = (bx >> 3) & 63, b = bx >> 9;
  int n0 = nt * 32;
  int tid = threadIdx.x;
  const float4* y4 = (const float4*)ws_y;
  for (int it = 0; it < 4; ++it) {
    int idx4 = it * 256 + tid;
    int nn = idx4 >> 5, c4 = idx4 & 31;
    float4 v = y4[((b * N_ + n0 + nn) * (long)T_ + t) * (C_ / 4) + c4];
    *(float4*)&tile[nn * 132 + c4 * 4] = v;
  }
  __syncthreads();
  int nn = tid & 31, cg = tid >> 5;
  for (int i = 0; i < 16; ++i) {
    int c = cg * 16 + i;
    out[((b * C_ + c) * (long)T_ + t) * N_ + n0 + nn] = tile[nn * 132 + c];
  }
}

extern "C" void kernel_launch(void* const* d_in, const int* in_sizes, int n_in,
                              void* d_out, int out_size, void* d_ws, size_t ws_size,
                              hipStream_t stream) {
  const float* x    = (const float*)d_in[0];
  const float* gam  = (const float*)d_in[1];
  const float* bet  = (const float*)d_in[2];
  const float* Win  = (const float*)d_in[3];
  const float* cw   = (const float*)d_in[4];
  const float* cb   = (const float*)d_in[5];
  const float* Wx   = (const float*)d_in[6];
  const float* Wdt  = (const float*)d_in[7];
  const float* bdt  = (const float*)d_in[8];
  const float* Alog = (const float*)d_in[9];
  const float* Dp   = (const float*)d_in[10];
  const float* Wout = (const float*)d_in[11];
  float* out = (float*)d_out;
  float* ws  = (float*)d_ws;   // 64 MiB: (B*N, T, C) fp32, in-place H -> y

  // split-weight storage: ws tail if it fits, else scribble d_out
  const size_t HBYTES = 67108864ull;                      // 64 MiB
  const size_t WBYTES = 131072ull + 65536ull + 8192ull;   // Win + Wout + Wx splits
  char* wtail;
  if (ws_size >= HBYTES + WBYTES) wtail = (char*)d_ws + HBYTES;
  else                            wtail = (char*)d_out;
  ushort_t* wsi = (ushort_t*)wtail;
  ushort_t* wso = (ushort_t*)(wtail + 131072);
  ushort_t* wsx = (ushort_t*)(wtail + 131072 + 65536);

  (void)hipFuncSetAttribute((const void*)k_mamba,
                            hipFuncAttributeMaxDynamicSharedMemorySize,
                            LDSW * 4);

  k_wsplit<<<4, 512, 0, stream>>>(Win, Wout, Wx, wsi, wso, wsx);
  k_ln<<<4096, 256, 0, stream>>>(x, gam, bet, ws);
  k_mamba<<<2048 / NSEQ, 512, LDSW * 4, stream>>>(ws, wsi, wso, wsx, cw, cb,
                                                  Wdt, bdt, Alog, Dp);
  k_out_tr<<<4096, 256, 0, stream>>>(ws, out);
}